// Round 11
// baseline (129.184 us; speedup 1.0000x reference)
//
#include <hip/hip_runtime.h>

// EuclideanCodebook: fp16 MFMA approx distance (r9 swizzled structure +
// m97-style double-buffered staging) + top-2 margin flag + split-K exact
// fp32 rescue.
// x: [N=32768][256] f32, embedding_sum: [K=2048][256] f32, usage: [K] f32
// out: quantized [N*256] f32, codes [N] f32

#define EPSV 1e-5f
#define DDIM 256
#define TAU  0.4f
#define BM   128     // rows per block (vq_mfma)
#define BCL  128     // clusters per tile
#define NCT  8       // cluster tiles per half (1024/128)
#define RPB  8       // rescue rows per group
#define KSPL 4       // rescue K split
#define NROWS 32768

typedef __attribute__((ext_vector_type(8))) _Float16 f16x8;
typedef __attribute__((ext_vector_type(4))) float f32x4;
typedef unsigned short u16;
typedef unsigned long long u64;

__device__ __forceinline__ u16 f2h(float f) {
    f = fminf(fmaxf(f, -60000.f), 60000.f);   // keep fp16 finite
    const _Float16 h = (_Float16)f;
    return __builtin_bit_cast(u16, h);
}
__device__ __forceinline__ u64 packdk(float d, int k) {
    unsigned u = __builtin_bit_cast(unsigned, d);
    u = (u & 0x80000000u) ? ~u : (u | 0x80000000u);   // sortable float
    return ((u64)u << 32) | (unsigned)k;
}

// ---------------- prep_e: emb, emb_t, e fp16, ||e||^2; zero counter ---------
__global__ void prep_e(const float* __restrict__ esum,
                       const float* __restrict__ usage,
                       float* __restrict__ emb,     // [K][256] f32
                       float* __restrict__ emb_t,   // [256][K] f32
                       u16* __restrict__ eh,        // [K][256] f16 bits
                       float* __restrict__ enorm2,  // [K]
                       int* __restrict__ counter,
                       int K) {
    if (blockIdx.x == 0 && threadIdx.x == 0) *counter = 0;
    const int k = blockIdx.x;
    const int d = threadIdx.x;                 // 256 threads
    const float u = fmaxf(usage[k], EPSV);
    const float e = esum[k * DDIM + d] / u;
    emb[k * DDIM + d] = e;
    emb_t[(size_t)d * K + k] = e;
    eh[k * DDIM + d] = f2h(e);

    float s = e * e;
    #pragma unroll
    for (int off = 32; off > 0; off >>= 1) s += __shfl_down(s, off, 64);
    __shared__ float ws[4];
    if ((threadIdx.x & 63) == 0) ws[threadIdx.x >> 6] = s;
    __syncthreads();
    if (threadIdx.x == 0) enorm2[k] = ws[0] + ws[1] + ws[2] + ws[3];
}

// ---------------- prep_x: x fp16 --------------------------------------------
__global__ void prep_x(const float* __restrict__ x, u16* __restrict__ xh) {
    const int n = blockIdx.x * 4 + (threadIdx.x >> 6);
    const int l = threadIdx.x & 63;
    const float4 v = *(const float4*)&x[(size_t)n * DDIM + l * 4];
    ushort4 h;
    h.x = f2h(v.x); h.y = f2h(v.y); h.z = f2h(v.z); h.w = f2h(v.w);
    *(ushort4*)&xh[(size_t)n * DDIM + l * 4] = h;
}

// ---------------- main: fp16 MFMA distance + running (min1, idx, min2) ------
// r9 structure (block = 128 rows x 1024 clusters, XOR-swizzled LDS, 0 bank
// conflicts) + m97 schedule: A/B tiles double-buffered; stage(round+1) is
// issued BEFORE the MFMAs of round r, so the end-of-round barrier's vmcnt
// drain finds the loads already landed (they had the whole MFMA phase in
// flight). One barrier per round (was two).
__global__ __launch_bounds__(256, 2) void vq_mfma(
        const u16* __restrict__ xh, const u16* __restrict__ eh,
        const float* __restrict__ enorm2,
        float* __restrict__ pm1, int* __restrict__ pi1,
        float* __restrict__ pm2, int N) {
    __shared__ __align__(16) u16 Als[2][BM * 64];    // 2 x 16 KB
    __shared__ __align__(16) u16 Bls[2][BCL * 64];   // 2 x 16 KB

    const int tid = threadIdx.x;
    const int l   = tid & 63;
    const int w   = tid >> 6;            // wave 0..3
    const int wr  = w >> 1, wc = w & 1;  // 2x2 wave grid (64x64 each)
    const int rowblk = blockIdx.x >> 1;
    const int half   = blockIdx.x & 1;
    const int n0     = rowblk * BM;
    const int cbase  = half * 1024;

    // swizzled source chunk for staging: row&7 == (l>>3)&7, chunk == l&7
    const int sgc = (l & 7) ^ ((l >> 3) & 7);

    // stage round rr (ct = rr>>2, ch = rr&3) into buffer buf
    auto stage = [&](int buf, int rr) {
        const int c0    = cbase + (rr >> 2) * BCL;
        const int colof = (rr & 3) * 64;
        #pragma unroll
        for (int j = 0; j < 4; ++j) {
            const int r = (w * 4 + j) * 8 + (l >> 3);
            const u16* ga = xh + (size_t)(n0 + r) * DDIM + colof + sgc * 8;
            __builtin_amdgcn_global_load_lds(
                (const __attribute__((address_space(1))) void*)ga,
                (__attribute__((address_space(3))) void*)((char*)Als[buf] + (w * 4 + j) * 1024),
                16, 0, 0);
            const u16* gb = eh + (size_t)(c0 + r) * DDIM + colof + sgc * 8;
            __builtin_amdgcn_global_load_lds(
                (const __attribute__((address_space(1))) void*)gb,
                (__attribute__((address_space(3))) void*)((char*)Bls[buf] + (w * 4 + j) * 1024),
                16, 0, 0);
        }
    };

    float m1[4][4], m2[4][4];
    int   i1[4][4];
    #pragma unroll
    for (int a = 0; a < 4; ++a)
        #pragma unroll
        for (int b = 0; b < 4; ++b) { m1[a][b] = 3.0e38f; m2[a][b] = 3.0e38f; i1[a][b] = 0; }

    stage(0, 0);
    __syncthreads();                     // prologue drain
    int buf = 0;

    for (int ct = 0; ct < NCT; ++ct) {
        const int c0 = cbase + ct * BCL;
        f32x4 acc[4][4];
        #pragma unroll
        for (int a = 0; a < 4; ++a)
            #pragma unroll
            for (int b = 0; b < 4; ++b) acc[a][b] = (f32x4){0.f, 0.f, 0.f, 0.f};

        for (int ch = 0; ch < 4; ++ch) {
            const int rr = ct * 4 + ch;
            if (rr + 1 < NCT * 4) stage(buf ^ 1, rr + 1);   // prefetch next round

            #pragma unroll
            for (int ks = 0; ks < 2; ++ks) {
                f16x8 af[4], bfr[4];
                #pragma unroll
                for (int f = 0; f < 4; ++f) {
                    const int arow = wr * 64 + f * 16 + (l & 15);
                    const int ac   = (ks * 4 + (l >> 4)) ^ (l & 7);   // arow&7 == l&7
                    af[f] = *(const f16x8*)((const char*)Als[buf] + arow * 128 + ac * 16);
                    const int brow = wc * 64 + f * 16 + (l & 15);
                    const int bc   = (ks * 4 + (l >> 4)) ^ (l & 7);
                    bfr[f] = *(const f16x8*)((const char*)Bls[buf] + brow * 128 + bc * 16);
                }
                #pragma unroll
                for (int fm = 0; fm < 4; ++fm)
                    #pragma unroll
                    for (int fn = 0; fn < 4; ++fn)
                        acc[fm][fn] = __builtin_amdgcn_mfma_f32_16x16x32_f16(
                            af[fm], bfr[fn], acc[fm][fn], 0, 0, 0);
            }
            __syncthreads();             // drains prefetch (landed under MFMA)
            buf ^= 1;
        }

        // fold into running (min1, idx, min2); k ascending
        #pragma unroll
        for (int fn = 0; fn < 4; ++fn) {
            const int k = c0 + wc * 64 + fn * 16 + (l & 15);
            const float en = enorm2[k];
            #pragma unroll
            for (int fm = 0; fm < 4; ++fm)
                #pragma unroll
                for (int i = 0; i < 4; ++i) {
                    const float s = fmaf(-2.0f, acc[fm][fn][i], en);
                    const bool lt1 = s < m1[fm][i];
                    m2[fm][i] = fminf(m2[fm][i], fmaxf(s, m1[fm][i]));
                    i1[fm][i] = lt1 ? k : i1[fm][i];
                    m1[fm][i] = fminf(m1[fm][i], s);
                }
        }
    }

    // reduce across the 16 lanes (l&15) sharing each row; ties -> smaller k
    #pragma unroll
    for (int fm = 0; fm < 4; ++fm)
        #pragma unroll
        for (int i = 0; i < 4; ++i) {
            float a1 = m1[fm][i], a2 = m2[fm][i];
            int ai = i1[fm][i];
            #pragma unroll
            for (int mask = 1; mask < 16; mask <<= 1) {
                const float b1 = __shfl_xor(a1, mask, 64);
                const int   bi = __shfl_xor(ai, mask, 64);
                const float b2 = __shfl_xor(a2, mask, 64);
                if (b1 < a1 || (b1 == a1 && bi < ai)) {
                    a2 = fminf(a1, fminf(a2, b2)); a1 = b1; ai = bi;
                } else {
                    a2 = fminf(b1, fminf(a2, b2));
                }
            }
            m1[fm][i] = a1; i1[fm][i] = ai; m2[fm][i] = a2;
        }

    // merge the two wave-columns via LDS, write per-(half,row) partials
    __syncthreads();
    float* Sm1 = (float*)Als;
    int*   Si1 = (int*)((char*)Als + 512);
    float* Sm2 = (float*)((char*)Als + 1024);
    if (wc == 0 && (l & 15) == 0) {
        #pragma unroll
        for (int fm = 0; fm < 4; ++fm)
            #pragma unroll
            for (int i = 0; i < 4; ++i) {
                const int r = wr * 64 + fm * 16 + (l >> 4) * 4 + i;
                Sm1[r] = m1[fm][i]; Si1[r] = i1[fm][i]; Sm2[r] = m2[fm][i];
            }
    }
    __syncthreads();
    if (wc == 1 && (l & 15) == 0) {
        #pragma unroll
        for (int fm = 0; fm < 4; ++fm)
            #pragma unroll
            for (int i = 0; i < 4; ++i) {
                const int r = wr * 64 + fm * 16 + (l >> 4) * 4 + i;
                const float b1 = Sm1[r], b2 = Sm2[r];
                const int   bi = Si1[r];
                float a1 = m1[fm][i], a2 = m2[fm][i];
                int   ai = i1[fm][i];
                float M1, M2; int MI;
                if (b1 < a1 || (b1 == a1 && bi < ai)) {
                    M1 = b1; MI = bi; M2 = fminf(a1, fminf(a2, b2));
                } else {
                    M1 = a1; MI = ai; M2 = fminf(b1, fminf(a2, b2));
                }
                const int n = n0 + r;
                pm1[(size_t)half * N + n] = M1;
                pi1[(size_t)half * N + n] = MI;
                pm2[(size_t)half * N + n] = M2;
            }
    }
}

// ---------------- combine halves -> codes + flag list + packed init ---------
__global__ void combine(const float* __restrict__ pm1, const int* __restrict__ pi1,
                        const float* __restrict__ pm2,
                        float* __restrict__ codes_f, int* __restrict__ codes_i,
                        int* __restrict__ list, int* __restrict__ counter,
                        u64* __restrict__ packed, int N) {
    const int n = blockIdx.x * 256 + threadIdx.x;
    const float a1 = pm1[n], a2 = pm2[n];
    const int   ai = pi1[n];
    const float b1 = pm1[(size_t)N + n], b2 = pm2[(size_t)N + n];
    const int   bi = pi1[(size_t)N + n];
    float M1, M2; int MI;
    if (b1 < a1 || (b1 == a1 && bi < ai)) {
        M1 = b1; MI = bi; M2 = fminf(a1, fminf(a2, b2));
    } else {
        M1 = a1; MI = ai; M2 = fminf(b1, fminf(a2, b2));
    }
    codes_i[n] = MI;
    codes_f[n] = (float)MI;
    if (M2 - M1 < TAU) {
        packed[n] = 0xFFFFFFFFFFFFFFFFull;
        const int idx = atomicAdd(counter, 1);
        list[idx] = n;
    }
}

// ---------------- rescue_c: exact fp32, 8 rows x 512-cluster work items -----
__global__ __launch_bounds__(256) void rescue_c(
        const float* __restrict__ x, const float* __restrict__ emb_t,
        const float* __restrict__ enorm2,
        const int* __restrict__ list, const int* __restrict__ counter,
        u64* __restrict__ packed, int K) {
    __shared__ float xs[RPB][DDIM];   // 8 KB
    const int t = threadIdx.x;
    const int l = t & 63;
    int cnt = *counter;
    cnt = cnt < 0 ? 0 : (cnt > NROWS ? NROWS : cnt);   // defensive clamp
    if (cnt == 0) return;
    const int nblk  = (cnt + RPB - 1) / RPB;
    const int items = nblk * KSPL;
    const int kc    = K / KSPL;       // 512

    for (int wi = blockIdx.x; wi < items; wi += gridDim.x) {
        const int g = wi >> 2;        // KSPL = 4
        const int q = wi & 3;
        const int base = g * RPB;
        int rows[RPB];
        #pragma unroll
        for (int r = 0; r < RPB; ++r) {
            int idx = base + r;
            rows[r] = list[idx < cnt ? idx : cnt - 1];
        }
        __syncthreads();              // previous iteration done reading xs
        #pragma unroll
        for (int r = 0; r < RPB; ++r)
            xs[r][t] = x[(size_t)rows[r] * DDIM + t];
        __syncthreads();

        float acc[RPB][2];
        #pragma unroll
        for (int r = 0; r < RPB; ++r) { acc[r][0] = 0.f; acc[r][1] = 0.f; }

        const float* eb = emb_t + q * kc + 2 * t;
        #pragma unroll 4
        for (int d = 0; d < DDIM; ++d) {
            const float2 e = *(const float2*)&eb[(size_t)d * K];
            #pragma unroll
            for (int r = 0; r < RPB; ++r) {
                const float xv = xs[r][d];
                acc[r][0] = fmaf(xv, e.x, acc[r][0]);
                acc[r][1] = fmaf(xv, e.y, acc[r][1]);
            }
        }

        const int k0 = q * kc + 2 * t;
        const float en0 = enorm2[k0], en1 = enorm2[k0 + 1];
        #pragma unroll
        for (int r = 0; r < RPB; ++r) {
            const float s0 = fmaf(-2.0f, acc[r][0], en0);
            const float s1 = fmaf(-2.0f, acc[r][1], en1);
            float bd = s0; int bk = k0;
            if (s1 < bd) { bd = s1; bk = k0 + 1; }
            #pragma unroll
            for (int m = 1; m < 64; m <<= 1) {
                const float od = __shfl_xor(bd, m, 64);
                const int   ok = __shfl_xor(bk, m, 64);
                if (od < bd || (od == bd && ok < bk)) { bd = od; bk = ok; }
            }
            if (l == 0) atomicMin(&packed[rows[r]], packdk(bd, bk));
        }
    }
}

// ---------------- fixup: unpack rescue winners into codes -------------------
__global__ void fixup(const u64* __restrict__ packed,
                      const int* __restrict__ list, const int* __restrict__ counter,
                      float* __restrict__ codes_f, int* __restrict__ codes_i) {
    int cnt = *counter;
    cnt = cnt < 0 ? 0 : (cnt > NROWS ? NROWS : cnt);   // defensive clamp
    const int i = blockIdx.x * 256 + threadIdx.x;
    if (i < cnt) {
        const int n = list[i];
        const int k = (int)(packed[n] & 0xFFFFFFFFull);
        codes_i[n] = k;
        codes_f[n] = (float)k;
    }
}

// ---------------- gather: quantized[n] = emb[code[n]] -----------------------
__global__ void gather_q(const float* __restrict__ emb,
                         const int* __restrict__ codes,
                         float* __restrict__ qout) {
    const int n = blockIdx.x * 4 + (threadIdx.x >> 6);
    const int c = threadIdx.x & 63;
    const int k = codes[n];
    *(float4*)&qout[(size_t)n * DDIM + c * 4] =
        *(const float4*)&emb[(size_t)k * DDIM + c * 4];
}

extern "C" void kernel_launch(void* const* d_in, const int* in_sizes, int n_in,
                              void* d_out, int out_size, void* d_ws, size_t ws_size,
                              hipStream_t stream) {
    const float* x     = (const float*)d_in[0];
    const float* esum  = (const float*)d_in[1];
    const float* usage = (const float*)d_in[2];
    const int K = in_sizes[2];                 // 2048
    const int N = in_sizes[0] / DDIM;          // 32768

    // workspace layout (packed first: 8B alignment)
    char* p = (char*)d_ws;
    u64*   packed  = (u64*)p;                  p += (size_t)N * 8;          // 256 KB
    float* emb     = (float*)p;                p += (size_t)K * DDIM * 4;   // 2 MB
    float* emb_t   = (float*)p;                p += (size_t)K * DDIM * 4;   // 2 MB
    float* enorm2  = (float*)p;                p += (size_t)K * 4;
    float* pm1     = (float*)p;                p += (size_t)2 * N * 4;
    float* pm2     = (float*)p;                p += (size_t)2 * N * 4;
    int*   pi1     = (int*)p;                  p += (size_t)2 * N * 4;
    int*   codes_i = (int*)p;                  p += (size_t)N * 4;
    int*   list    = (int*)p;                  p += (size_t)N * 4;
    int*   counter = (int*)p;                  p += 256;
    u16*   xh      = (u16*)p;                  p += (size_t)N * DDIM * 2;   // 16 MB
    u16*   eh      = (u16*)p;                  p += (size_t)K * DDIM * 2;   // 1 MB

    float* qout    = (float*)d_out;            // N*256
    float* codes_f = qout + (size_t)N * DDIM;  // N

    prep_e<<<K, 256, 0, stream>>>(esum, usage, emb, emb_t, eh, enorm2, counter, K);
    prep_x<<<N / 4, 256, 0, stream>>>(x, xh);
    vq_mfma<<<(N / BM) * 2, 256, 0, stream>>>(xh, eh, enorm2, pm1, pi1, pm2, N);
    combine<<<N / 256, 256, 0, stream>>>(pm1, pi1, pm2, codes_f, codes_i,
                                         list, counter, packed, N);
    rescue_c<<<1024, 256, 0, stream>>>(x, emb_t, enorm2, list, counter, packed, K);
    fixup<<<N / 256, 256, 0, stream>>>(packed, list, counter, codes_f, codes_i);
    gather_q<<<N / 4, 256, 0, stream>>>(emb, codes_i, qout);
}

// Round 12
// 128.410 us; speedup vs baseline: 1.0060x; 1.0060x over previous
//
#include <hip/hip_runtime.h>

// EuclideanCodebook: fp16 MFMA approx distance (r9 swizzled single-buffer
// structure + cluster-quarter grid + bijective XCD swizzle + med3 fold)
// + top-2 margin flag + split-K exact fp32 rescue.
// x: [N=32768][256] f32, embedding_sum: [K=2048][256] f32, usage: [K] f32
// out: quantized [N*256] f32, codes [N] f32

#define EPSV 1e-5f
#define DDIM 256
#define TAU  0.4f
#define BM   128     // rows per block (vq_mfma)
#define BCL  128     // clusters per tile
#define NPART 4      // cluster quarters (512 each)
#define NCT  4       // cluster tiles per quarter (512/128)
#define RPB  8       // rescue rows per group
#define KSPL 4       // rescue K split
#define NROWS 32768

typedef __attribute__((ext_vector_type(8))) _Float16 f16x8;
typedef __attribute__((ext_vector_type(4))) float f32x4;
typedef unsigned short u16;
typedef unsigned long long u64;

__device__ __forceinline__ u16 f2h(float f) {
    f = fminf(fmaxf(f, -60000.f), 60000.f);   // keep fp16 finite
    const _Float16 h = (_Float16)f;
    return __builtin_bit_cast(u16, h);
}
__device__ __forceinline__ u64 packdk(float d, int k) {
    unsigned u = __builtin_bit_cast(unsigned, d);
    u = (u & 0x80000000u) ? ~u : (u | 0x80000000u);   // sortable float
    return ((u64)u << 32) | (unsigned)k;
}

// ---------------- prep_e: emb, emb_t, e fp16, ||e||^2; zero counter ---------
__global__ void prep_e(const float* __restrict__ esum,
                       const float* __restrict__ usage,
                       float* __restrict__ emb,     // [K][256] f32
                       float* __restrict__ emb_t,   // [256][K] f32
                       u16* __restrict__ eh,        // [K][256] f16 bits
                       float* __restrict__ enorm2,  // [K]
                       int* __restrict__ counter,
                       int K) {
    if (blockIdx.x == 0 && threadIdx.x == 0) *counter = 0;
    const int k = blockIdx.x;
    const int d = threadIdx.x;                 // 256 threads
    const float u = fmaxf(usage[k], EPSV);
    const float e = esum[k * DDIM + d] / u;
    emb[k * DDIM + d] = e;
    emb_t[(size_t)d * K + k] = e;
    eh[k * DDIM + d] = f2h(e);

    float s = e * e;
    #pragma unroll
    for (int off = 32; off > 0; off >>= 1) s += __shfl_down(s, off, 64);
    __shared__ float ws[4];
    if ((threadIdx.x & 63) == 0) ws[threadIdx.x >> 6] = s;
    __syncthreads();
    if (threadIdx.x == 0) enorm2[k] = ws[0] + ws[1] + ws[2] + ws[3];
}

// ---------------- prep_x: x fp16 --------------------------------------------
__global__ void prep_x(const float* __restrict__ x, u16* __restrict__ xh) {
    const int n = blockIdx.x * 4 + (threadIdx.x >> 6);
    const int l = threadIdx.x & 63;
    const float4 v = *(const float4*)&x[(size_t)n * DDIM + l * 4];
    ushort4 h;
    h.x = f2h(v.x); h.y = f2h(v.y); h.z = f2h(v.z); h.w = f2h(v.w);
    *(ushort4*)&xh[(size_t)n * DDIM + l * 4] = h;
}

// ---------------- main: fp16 MFMA distance + running (min1, idx, min2) ------
// r9 structure (XOR-swizzled LDS, single-buffer, 0 bank conflicts), block =
// 128 rows x 512 clusters (quarter) -> grid 1024 for 4 blocks/CU residency.
// Bijective XCD swizzle keeps all 4 quarters of a rowblk on one XCD so the
// A rows are fetched from HBM once (L2-resident thereafter). med3 fold.
__global__ __launch_bounds__(256, 2) void vq_mfma(
        const u16* __restrict__ xh, const u16* __restrict__ eh,
        const float* __restrict__ enorm2,
        float* __restrict__ pm1, int* __restrict__ pi1,
        float* __restrict__ pm2, int N) {
    __shared__ __align__(16) u16 Als[BM * 64];    // 16 KB
    __shared__ __align__(16) u16 Bls[BCL * 64];   // 16 KB

    const int tid = threadIdx.x;
    const int l   = tid & 63;
    const int w   = tid >> 6;            // wave 0..3
    const int wr  = w >> 1, wc = w & 1;  // 2x2 wave grid (64x64 each)

    // bijective XCD swizzle: nwg = (N/BM)*NPART (1024), divisible by 8
    const int nwg = (N / BM) * NPART;
    const int q   = nwg >> 3;
    const int pb  = blockIdx.x;
    const int logical = (pb & 7) * q + (pb >> 3);
    const int rowblk  = logical >> 2;    // NPART = 4
    const int part    = logical & 3;
    const int n0      = rowblk * BM;
    const int cbase   = part * 512;

    float m1[4][4], m2[4][4];
    int   i1[4][4];
    #pragma unroll
    for (int a = 0; a < 4; ++a)
        #pragma unroll
        for (int b = 0; b < 4; ++b) { m1[a][b] = 3.0e38f; m2[a][b] = 3.0e38f; i1[a][b] = 0; }

    // swizzled source chunk for staging: row&7 == (l>>3)&7, chunk == l&7
    const int sgc = (l & 7) ^ ((l >> 3) & 7);

    for (int ct = 0; ct < NCT; ++ct) {
        const int c0 = cbase + ct * BCL;
        f32x4 acc[4][4];
        #pragma unroll
        for (int a = 0; a < 4; ++a)
            #pragma unroll
            for (int b = 0; b < 4; ++b) acc[a][b] = (f32x4){0.f, 0.f, 0.f, 0.f};

        for (int ch = 0; ch < 4; ++ch) {       // 256 = 4 x 64 inner dims
            const int colof = ch * 64;

            __syncthreads();
            #pragma unroll
            for (int j = 0; j < 4; ++j) {
                const int r = (w * 4 + j) * 8 + (l >> 3);
                const u16* ga = xh + (size_t)(n0 + r) * DDIM + colof + sgc * 8;
                __builtin_amdgcn_global_load_lds(
                    (const __attribute__((address_space(1))) void*)ga,
                    (__attribute__((address_space(3))) void*)((char*)Als + (w * 4 + j) * 1024),
                    16, 0, 0);
            }
            #pragma unroll
            for (int j = 0; j < 4; ++j) {
                const int r = (w * 4 + j) * 8 + (l >> 3);
                const u16* gb = eh + (size_t)(c0 + r) * DDIM + colof + sgc * 8;
                __builtin_amdgcn_global_load_lds(
                    (const __attribute__((address_space(1))) void*)gb,
                    (__attribute__((address_space(3))) void*)((char*)Bls + (w * 4 + j) * 1024),
                    16, 0, 0);
            }
            __syncthreads();

            #pragma unroll
            for (int ks = 0; ks < 2; ++ks) {
                f16x8 af[4], bfr[4];
                #pragma unroll
                for (int f = 0; f < 4; ++f) {
                    const int arow = wr * 64 + f * 16 + (l & 15);
                    const int ac   = (ks * 4 + (l >> 4)) ^ (l & 7);   // arow&7 == l&7
                    af[f] = *(const f16x8*)((const char*)Als + arow * 128 + ac * 16);
                    const int brow = wc * 64 + f * 16 + (l & 15);
                    const int bc   = (ks * 4 + (l >> 4)) ^ (l & 7);
                    bfr[f] = *(const f16x8*)((const char*)Bls + brow * 128 + bc * 16);
                }
                #pragma unroll
                for (int fm = 0; fm < 4; ++fm)
                    #pragma unroll
                    for (int fn = 0; fn < 4; ++fn)
                        acc[fm][fn] = __builtin_amdgcn_mfma_f32_16x16x32_f16(
                            af[fm], bfr[fn], acc[fm][fn], 0, 0, 0);
            }
        }

        // fold into running (min1, idx, min2); k ascending; m2 via med3
        #pragma unroll
        for (int fn = 0; fn < 4; ++fn) {
            const int k = c0 + wc * 64 + fn * 16 + (l & 15);
            const float en = enorm2[k];
            #pragma unroll
            for (int fm = 0; fm < 4; ++fm)
                #pragma unroll
                for (int i = 0; i < 4; ++i) {
                    const float s = fmaf(-2.0f, acc[fm][fn][i], en);
                    const bool lt1 = s < m1[fm][i];
                    m2[fm][i] = __builtin_amdgcn_fmed3f(s, m1[fm][i], m2[fm][i]);
                    i1[fm][i] = lt1 ? k : i1[fm][i];
                    m1[fm][i] = fminf(m1[fm][i], s);
                }
        }
    }

    // reduce across the 16 lanes (l&15) sharing each row; ties -> smaller k
    #pragma unroll
    for (int fm = 0; fm < 4; ++fm)
        #pragma unroll
        for (int i = 0; i < 4; ++i) {
            float a1 = m1[fm][i], a2 = m2[fm][i];
            int ai = i1[fm][i];
            #pragma unroll
            for (int mask = 1; mask < 16; mask <<= 1) {
                const float b1 = __shfl_xor(a1, mask, 64);
                const int   bi = __shfl_xor(ai, mask, 64);
                const float b2 = __shfl_xor(a2, mask, 64);
                if (b1 < a1 || (b1 == a1 && bi < ai)) {
                    a2 = fminf(a1, fminf(a2, b2)); a1 = b1; ai = bi;
                } else {
                    a2 = fminf(b1, fminf(a2, b2));
                }
            }
            m1[fm][i] = a1; i1[fm][i] = ai; m2[fm][i] = a2;
        }

    // merge the two wave-columns via LDS, write per-(part,row) partials
    __syncthreads();
    float* Sm1 = (float*)Als;
    int*   Si1 = (int*)((char*)Als + 512);
    float* Sm2 = (float*)((char*)Als + 1024);
    if (wc == 0 && (l & 15) == 0) {
        #pragma unroll
        for (int fm = 0; fm < 4; ++fm)
            #pragma unroll
            for (int i = 0; i < 4; ++i) {
                const int r = wr * 64 + fm * 16 + (l >> 4) * 4 + i;
                Sm1[r] = m1[fm][i]; Si1[r] = i1[fm][i]; Sm2[r] = m2[fm][i];
            }
    }
    __syncthreads();
    if (wc == 1 && (l & 15) == 0) {
        #pragma unroll
        for (int fm = 0; fm < 4; ++fm)
            #pragma unroll
            for (int i = 0; i < 4; ++i) {
                const int r = wr * 64 + fm * 16 + (l >> 4) * 4 + i;
                const float b1 = Sm1[r], b2 = Sm2[r];
                const int   bi = Si1[r];
                float a1 = m1[fm][i], a2 = m2[fm][i];
                int   ai = i1[fm][i];
                float M1, M2; int MI;
                if (b1 < a1 || (b1 == a1 && bi < ai)) {
                    M1 = b1; MI = bi; M2 = fminf(a1, fminf(a2, b2));
                } else {
                    M1 = a1; MI = ai; M2 = fminf(b1, fminf(a2, b2));
                }
                const int n = n0 + r;
                pm1[(size_t)part * N + n] = M1;
                pi1[(size_t)part * N + n] = MI;
                pm2[(size_t)part * N + n] = M2;
            }
    }
}

// ---------------- combine quarters -> codes + flag list + packed init -------
__global__ void combine(const float* __restrict__ pm1, const int* __restrict__ pi1,
                        const float* __restrict__ pm2,
                        float* __restrict__ codes_f, int* __restrict__ codes_i,
                        int* __restrict__ list, int* __restrict__ counter,
                        u64* __restrict__ packed, int N) {
    const int n = blockIdx.x * 256 + threadIdx.x;
    float M1 = pm1[n], M2 = pm2[n];
    int   MI = pi1[n];
    #pragma unroll
    for (int j = 1; j < NPART; ++j) {
        const float b1 = pm1[(size_t)j * N + n], b2 = pm2[(size_t)j * N + n];
        const int   bi = pi1[(size_t)j * N + n];
        if (b1 < M1 || (b1 == M1 && bi < MI)) {
            M2 = fminf(M1, fminf(M2, b2)); M1 = b1; MI = bi;
        } else {
            M2 = fminf(b1, fminf(M2, b2));
        }
    }
    codes_i[n] = MI;
    codes_f[n] = (float)MI;
    if (M2 - M1 < TAU) {
        packed[n] = 0xFFFFFFFFFFFFFFFFull;
        const int idx = atomicAdd(counter, 1);
        list[idx] = n;
    }
}

// ---------------- rescue_c: exact fp32, 8 rows x 512-cluster work items -----
__global__ __launch_bounds__(256) void rescue_c(
        const float* __restrict__ x, const float* __restrict__ emb_t,
        const float* __restrict__ enorm2,
        const int* __restrict__ list, const int* __restrict__ counter,
        u64* __restrict__ packed, int K) {
    __shared__ float xs[RPB][DDIM];   // 8 KB
    const int t = threadIdx.x;
    const int l = t & 63;
    int cnt = *counter;
    cnt = cnt < 0 ? 0 : (cnt > NROWS ? NROWS : cnt);   // defensive clamp
    if (cnt == 0) return;
    const int nblk  = (cnt + RPB - 1) / RPB;
    const int items = nblk * KSPL;
    const int kc    = K / KSPL;       // 512

    for (int wi = blockIdx.x; wi < items; wi += gridDim.x) {
        const int g = wi >> 2;        // KSPL = 4
        const int q = wi & 3;
        const int base = g * RPB;
        int rows[RPB];
        #pragma unroll
        for (int r = 0; r < RPB; ++r) {
            int idx = base + r;
            rows[r] = list[idx < cnt ? idx : cnt - 1];
        }
        __syncthreads();              // previous iteration done reading xs
        #pragma unroll
        for (int r = 0; r < RPB; ++r)
            xs[r][t] = x[(size_t)rows[r] * DDIM + t];
        __syncthreads();

        float acc[RPB][2];
        #pragma unroll
        for (int r = 0; r < RPB; ++r) { acc[r][0] = 0.f; acc[r][1] = 0.f; }

        const float* eb = emb_t + q * kc + 2 * t;
        #pragma unroll 4
        for (int d = 0; d < DDIM; ++d) {
            const float2 e = *(const float2*)&eb[(size_t)d * K];
            #pragma unroll
            for (int r = 0; r < RPB; ++r) {
                const float xv = xs[r][d];
                acc[r][0] = fmaf(xv, e.x, acc[r][0]);
                acc[r][1] = fmaf(xv, e.y, acc[r][1]);
            }
        }

        const int k0 = q * kc + 2 * t;
        const float en0 = enorm2[k0], en1 = enorm2[k0 + 1];
        #pragma unroll
        for (int r = 0; r < RPB; ++r) {
            const float s0 = fmaf(-2.0f, acc[r][0], en0);
            const float s1 = fmaf(-2.0f, acc[r][1], en1);
            float bd = s0; int bk = k0;
            if (s1 < bd) { bd = s1; bk = k0 + 1; }
            #pragma unroll
            for (int m = 1; m < 64; m <<= 1) {
                const float od = __shfl_xor(bd, m, 64);
                const int   ok = __shfl_xor(bk, m, 64);
                if (od < bd || (od == bd && ok < bk)) { bd = od; bk = ok; }
            }
            if (l == 0) atomicMin(&packed[rows[r]], packdk(bd, bk));
        }
    }
}

// ---------------- fixup: unpack rescue winners into codes -------------------
__global__ void fixup(const u64* __restrict__ packed,
                      const int* __restrict__ list, const int* __restrict__ counter,
                      float* __restrict__ codes_f, int* __restrict__ codes_i) {
    int cnt = *counter;
    cnt = cnt < 0 ? 0 : (cnt > NROWS ? NROWS : cnt);   // defensive clamp
    const int i = blockIdx.x * 256 + threadIdx.x;
    if (i < cnt) {
        const int n = list[i];
        const int k = (int)(packed[n] & 0xFFFFFFFFull);
        codes_i[n] = k;
        codes_f[n] = (float)k;
    }
}

// ---------------- gather: quantized[n] = emb[code[n]] -----------------------
__global__ void gather_q(const float* __restrict__ emb,
                         const int* __restrict__ codes,
                         float* __restrict__ qout) {
    const int n = blockIdx.x * 4 + (threadIdx.x >> 6);
    const int c = threadIdx.x & 63;
    const int k = codes[n];
    *(float4*)&qout[(size_t)n * DDIM + c * 4] =
        *(const float4*)&emb[(size_t)k * DDIM + c * 4];
}

extern "C" void kernel_launch(void* const* d_in, const int* in_sizes, int n_in,
                              void* d_out, int out_size, void* d_ws, size_t ws_size,
                              hipStream_t stream) {
    const float* x     = (const float*)d_in[0];
    const float* esum  = (const float*)d_in[1];
    const float* usage = (const float*)d_in[2];
    const int K = in_sizes[2];                 // 2048
    const int N = in_sizes[0] / DDIM;          // 32768

    // workspace layout (packed first: 8B alignment)
    char* p = (char*)d_ws;
    u64*   packed  = (u64*)p;                  p += (size_t)N * 8;             // 256 KB
    float* emb     = (float*)p;                p += (size_t)K * DDIM * 4;      // 2 MB
    float* emb_t   = (float*)p;                p += (size_t)K * DDIM * 4;      // 2 MB
    float* enorm2  = (float*)p;                p += (size_t)K * 4;
    float* pm1     = (float*)p;                p += (size_t)NPART * N * 4;     // 512 KB
    float* pm2     = (float*)p;                p += (size_t)NPART * N * 4;     // 512 KB
    int*   pi1     = (int*)p;                  p += (size_t)NPART * N * 4;     // 512 KB
    int*   codes_i = (int*)p;                  p += (size_t)N * 4;
    int*   list    = (int*)p;                  p += (size_t)N * 4;
    int*   counter = (int*)p;                  p += 256;
    u16*   xh      = (u16*)p;                  p += (size_t)N * DDIM * 2;      // 16 MB
    u16*   eh      = (u16*)p;                  p += (size_t)K * DDIM * 2;      // 1 MB

    float* qout    = (float*)d_out;            // N*256
    float* codes_f = qout + (size_t)N * DDIM;  // N

    prep_e<<<K, 256, 0, stream>>>(esum, usage, emb, emb_t, eh, enorm2, counter, K);
    prep_x<<<N / 4, 256, 0, stream>>>(x, xh);
    vq_mfma<<<(N / BM) * NPART, 256, 0, stream>>>(xh, eh, enorm2, pm1, pi1, pm2, N);
    combine<<<N / 256, 256, 0, stream>>>(pm1, pi1, pm2, codes_f, codes_i,
                                         list, counter, packed, N);
    rescue_c<<<1024, 256, 0, stream>>>(x, emb_t, enorm2, list, counter, packed, K);
    fixup<<<N / 256, 256, 0, stream>>>(packed, list, counter, codes_f, codes_i);
    gather_q<<<N / 4, 256, 0, stream>>>(emb, codes_i, qout);
}

// Round 13
// 121.615 us; speedup vs baseline: 1.0622x; 1.0559x over previous
//
#include <hip/hip_runtime.h>

// EuclideanCodebook: fp16 MFMA approx distance (r9/r11 swizzled structure,
// packed-u32 argmin state for 3-waves/SIMD occupancy) + margin flag +
// split-K exact fp32 rescue. 5-kernel pipeline.
// x: [N=32768][256] f32, embedding_sum: [K=2048][256] f32, usage: [K] f32
// out: quantized [N*256] f32, codes [N] f32

#define EPSV 1e-5f
#define TAU  0.4f
#define DDIM 256
#define BM   128     // rows per block (vq_mfma)
#define BCL  128     // clusters per tile
#define NPART 4      // cluster quarters (512 each)
#define NCT  4       // cluster tiles per quarter
#define RPB  8       // rescue rows per group
#define KSPL 4       // rescue K split
#define NROWS 32768

typedef __attribute__((ext_vector_type(8))) _Float16 f16x8;
typedef __attribute__((ext_vector_type(4))) float f32x4;
typedef unsigned short u16;
typedef unsigned u32;
typedef unsigned long long u64;

__device__ __forceinline__ u16 f2h(float f) {
    f = fminf(fmaxf(f, -60000.f), 60000.f);   // keep fp16 finite
    const _Float16 h = (_Float16)f;
    return __builtin_bit_cast(u16, h);
}
__device__ __forceinline__ u32 umn(u32 a, u32 b) { return a < b ? a : b; }
__device__ __forceinline__ u32 umx(u32 a, u32 b) { return a > b ? a : b; }
__device__ __forceinline__ float unsort(u32 u) {
    // inverse of (neg ? ~u : u|0x80000000); low 11 bits already cleared
    const u32 v = (u & 0x80000000u) ? (u & 0x7FFFFFFFu) : ~u;
    return __builtin_bit_cast(float, v);
}
__device__ __forceinline__ u64 packdk(float d, int k) {
    u32 u = __builtin_bit_cast(u32, d);
    u = (u & 0x80000000u) ? ~u : (u | 0x80000000u);   // sortable float
    return ((u64)u << 32) | (u32)k;
}

// ---------------- prep: emb, emb_t, eh, enorm2, xh; zero counter ------------
__global__ void prep(const float* __restrict__ esum,
                     const float* __restrict__ usage,
                     const float* __restrict__ x,
                     float* __restrict__ emb,     // [K][256] f32
                     float* __restrict__ emb_t,   // [256][K] f32
                     u16* __restrict__ eh,        // [K][256] f16 bits
                     float* __restrict__ enorm2,  // [K]
                     u16* __restrict__ xh,        // [N][256] f16 bits
                     int* __restrict__ counter,
                     int K) {
    const int b = blockIdx.x;
    if (b == 0 && threadIdx.x == 0) *counter = 0;
    if (b < K) {
        const int k = b;
        const int d = threadIdx.x;             // 256 threads
        const float u = fmaxf(usage[k], EPSV);
        const float e = esum[k * DDIM + d] / u;
        emb[k * DDIM + d] = e;
        emb_t[(size_t)d * K + k] = e;
        eh[k * DDIM + d] = f2h(e);

        float s = e * e;
        #pragma unroll
        for (int off = 32; off > 0; off >>= 1) s += __shfl_down(s, off, 64);
        __shared__ float ws[4];
        if ((threadIdx.x & 63) == 0) ws[threadIdx.x >> 6] = s;
        __syncthreads();
        if (threadIdx.x == 0) enorm2[k] = ws[0] + ws[1] + ws[2] + ws[3];
    } else {
        const int n = (b - K) * 4 + (threadIdx.x >> 6);
        const int l = threadIdx.x & 63;
        const float4 v = *(const float4*)&x[(size_t)n * DDIM + l * 4];
        ushort4 h;
        h.x = f2h(v.x); h.y = f2h(v.y); h.z = f2h(v.z); h.w = f2h(v.w);
        *(ushort4*)&xh[(size_t)n * DDIM + l * 4] = h;
    }
}

// ---------------- main: fp16 MFMA distance + packed (min1,min2) -------------
// r9/r11 structure: XOR-swizzled LDS (0 bank conflicts), block = 128 rows x
// 512 clusters, bijective XCD swizzle (A L2-resident, FETCH 12MB). NEW:
// argmin state packed as (sortable(s)&~0x7FF)|k in u32 — drops i1[16] VGPRs
// so arch+acc regs fit 3 waves/SIMD (unified VGPR/AGPR file: 176->160).
// Quantization-induced ties land under TAU and are rescued exactly.
__global__ __launch_bounds__(256, 2) void vq_mfma(
        const u16* __restrict__ xh, const u16* __restrict__ eh,
        const float* __restrict__ enorm2,
        u32* __restrict__ pp1, u32* __restrict__ pp2, int N) {
    __shared__ __align__(16) u16 Als[BM * 64];    // 16 KB
    __shared__ __align__(16) u16 Bls[BCL * 64];   // 16 KB

    const int tid = threadIdx.x;
    const int l   = tid & 63;
    const int w   = tid >> 6;            // wave 0..3
    const int wr  = w >> 1, wc = w & 1;  // 2x2 wave grid (64x64 each)

    // bijective XCD swizzle: nwg = (N/BM)*NPART (1024), divisible by 8
    const int nwg = (N / BM) * NPART;
    const int q   = nwg >> 3;
    const int pb  = blockIdx.x;
    const int logical = (pb & 7) * q + (pb >> 3);
    const int rowblk  = logical >> 2;    // NPART = 4
    const int part    = logical & 3;
    const int n0      = rowblk * BM;
    const int cbase   = part * 512;

    u32 m1p[4][4], m2p[4][4];
    #pragma unroll
    for (int a = 0; a < 4; ++a)
        #pragma unroll
        for (int b = 0; b < 4; ++b) { m1p[a][b] = 0xFFFFFFFFu; m2p[a][b] = 0xFFFFFFFFu; }

    // swizzled source chunk for staging: row&7 == (l>>3)&7, chunk == l&7
    const int sgc = (l & 7) ^ ((l >> 3) & 7);

    for (int ct = 0; ct < NCT; ++ct) {
        const int c0 = cbase + ct * BCL;
        f32x4 acc[4][4];
        #pragma unroll
        for (int a = 0; a < 4; ++a)
            #pragma unroll
            for (int b = 0; b < 4; ++b) acc[a][b] = (f32x4){0.f, 0.f, 0.f, 0.f};

        for (int ch = 0; ch < 4; ++ch) {       // 256 = 4 x 64 inner dims
            const int colof = ch * 64;

            __syncthreads();
            #pragma unroll
            for (int j = 0; j < 4; ++j) {
                const int r = (w * 4 + j) * 8 + (l >> 3);
                const u16* ga = xh + (size_t)(n0 + r) * DDIM + colof + sgc * 8;
                __builtin_amdgcn_global_load_lds(
                    (const __attribute__((address_space(1))) void*)ga,
                    (__attribute__((address_space(3))) void*)((char*)Als + (w * 4 + j) * 1024),
                    16, 0, 0);
            }
            #pragma unroll
            for (int j = 0; j < 4; ++j) {
                const int r = (w * 4 + j) * 8 + (l >> 3);
                const u16* gb = eh + (size_t)(c0 + r) * DDIM + colof + sgc * 8;
                __builtin_amdgcn_global_load_lds(
                    (const __attribute__((address_space(1))) void*)gb,
                    (__attribute__((address_space(3))) void*)((char*)Bls + (w * 4 + j) * 1024),
                    16, 0, 0);
            }
            __syncthreads();

            #pragma unroll
            for (int ks = 0; ks < 2; ++ks) {
                f16x8 af[4], bfr[4];
                #pragma unroll
                for (int f = 0; f < 4; ++f) {
                    const int arow = wr * 64 + f * 16 + (l & 15);
                    const int ac   = (ks * 4 + (l >> 4)) ^ (l & 7);   // arow&7 == l&7
                    af[f] = *(const f16x8*)((const char*)Als + arow * 128 + ac * 16);
                    const int brow = wc * 64 + f * 16 + (l & 15);
                    const int bc   = (ks * 4 + (l >> 4)) ^ (l & 7);
                    bfr[f] = *(const f16x8*)((const char*)Bls + brow * 128 + bc * 16);
                }
                #pragma unroll
                for (int fm = 0; fm < 4; ++fm)
                    #pragma unroll
                    for (int fn = 0; fn < 4; ++fn)
                        acc[fm][fn] = __builtin_amdgcn_mfma_f32_16x16x32_f16(
                            af[fm], bfr[fn], acc[fm][fn], 0, 0, 0);
            }
        }

        // fold: pack (s,k) sortable and track (min1, min2) as u32
        #pragma unroll
        for (int fn = 0; fn < 4; ++fn) {
            const int k = c0 + wc * 64 + fn * 16 + (l & 15);
            const float en = enorm2[k];
            #pragma unroll
            for (int fm = 0; fm < 4; ++fm)
                #pragma unroll
                for (int i = 0; i < 4; ++i) {
                    const float s = fmaf(-2.0f, acc[fm][fn][i], en);
                    u32 u = __builtin_bit_cast(u32, s);
                    u = ((int)u < 0) ? ~u : (u | 0x80000000u);
                    const u32 p = (u & 0xFFFFF800u) | (u32)k;
                    m2p[fm][i] = umn(m2p[fm][i], umx(p, m1p[fm][i]));
                    m1p[fm][i] = umn(m1p[fm][i], p);
                }
        }
    }

    // reduce across the 16 lanes (l&15) sharing each row
    #pragma unroll
    for (int fm = 0; fm < 4; ++fm)
        #pragma unroll
        for (int i = 0; i < 4; ++i) {
            u32 p1 = m1p[fm][i], p2 = m2p[fm][i];
            #pragma unroll
            for (int mask = 1; mask < 16; mask <<= 1) {
                const u32 o1 = (u32)__shfl_xor((int)p1, mask, 64);
                const u32 o2 = (u32)__shfl_xor((int)p2, mask, 64);
                p2 = umn(umn(p2, o2), umx(p1, o1));
                p1 = umn(p1, o1);
            }
            m1p[fm][i] = p1; m2p[fm][i] = p2;
        }

    // merge the two wave-columns via LDS, write per-(part,row) partials
    __syncthreads();
    u32* S1 = (u32*)Als;                   // [128]
    u32* S2 = (u32*)((char*)Als + 512);    // [128]
    if (wc == 0 && (l & 15) == 0) {
        #pragma unroll
        for (int fm = 0; fm < 4; ++fm)
            #pragma unroll
            for (int i = 0; i < 4; ++i) {
                const int r = wr * 64 + fm * 16 + (l >> 4) * 4 + i;
                S1[r] = m1p[fm][i]; S2[r] = m2p[fm][i];
            }
    }
    __syncthreads();
    if (wc == 1 && (l & 15) == 0) {
        #pragma unroll
        for (int fm = 0; fm < 4; ++fm)
            #pragma unroll
            for (int i = 0; i < 4; ++i) {
                const int r = wr * 64 + fm * 16 + (l >> 4) * 4 + i;
                const u32 o1 = S1[r], o2 = S2[r];
                u32 p1 = m1p[fm][i], p2 = m2p[fm][i];
                const u32 M2 = umn(umn(p2, o2), umx(p1, o1));
                const u32 M1 = umn(p1, o1);
                const int n = n0 + r;
                pp1[(size_t)part * N + n] = M1;
                pp2[(size_t)part * N + n] = M2;
            }
    }
}

// ---------------- combine quarters -> codes + flags + rescue list -----------
__global__ void combine(const u32* __restrict__ pp1, const u32* __restrict__ pp2,
                        int* __restrict__ codes_i, int* __restrict__ flags,
                        int* __restrict__ list, int* __restrict__ counter,
                        u64* __restrict__ packed, int N) {
    const int n = blockIdx.x * 256 + threadIdx.x;
    u32 p1 = pp1[n], p2 = pp2[n];
    #pragma unroll
    for (int j = 1; j < NPART; ++j) {
        const u32 o1 = pp1[(size_t)j * N + n], o2 = pp2[(size_t)j * N + n];
        p2 = umn(umn(p2, o2), umx(p1, o1));
        p1 = umn(p1, o1);
    }
    codes_i[n] = (int)(p1 & 0x7FFu);
    const float m1f = unsort(p1 & 0xFFFFF800u);
    const float m2f = unsort(p2 & 0xFFFFF800u);
    const int fl = (m2f - m1f < TAU) ? 1 : 0;
    flags[n] = fl;
    if (fl) {
        packed[n] = 0xFFFFFFFFFFFFFFFFull;
        const int idx = atomicAdd(counter, 1);
        list[idx] = n;
    }
}

// ---------------- rescue_c: exact fp32, 8 rows x 512-cluster work items -----
__global__ __launch_bounds__(256) void rescue_c(
        const float* __restrict__ x, const float* __restrict__ emb_t,
        const float* __restrict__ enorm2,
        const int* __restrict__ list, const int* __restrict__ counter,
        u64* __restrict__ packed, int K) {
    __shared__ float xs[RPB][DDIM];   // 8 KB
    const int t = threadIdx.x;
    const int l = t & 63;
    int cnt = *counter;
    cnt = cnt < 0 ? 0 : (cnt > NROWS ? NROWS : cnt);   // defensive clamp
    if (cnt == 0) return;
    const int nblk  = (cnt + RPB - 1) / RPB;
    const int items = nblk * KSPL;
    const int kc    = K / KSPL;       // 512

    for (int wi = blockIdx.x; wi < items; wi += gridDim.x) {
        const int g = wi >> 2;        // KSPL = 4
        const int q = wi & 3;
        const int base = g * RPB;
        int rows[RPB];
        #pragma unroll
        for (int r = 0; r < RPB; ++r) {
            int idx = base + r;
            rows[r] = list[idx < cnt ? idx : cnt - 1];
        }
        __syncthreads();              // previous iteration done reading xs
        #pragma unroll
        for (int r = 0; r < RPB; ++r)
            xs[r][t] = x[(size_t)rows[r] * DDIM + t];
        __syncthreads();

        float acc[RPB][2];
        #pragma unroll
        for (int r = 0; r < RPB; ++r) { acc[r][0] = 0.f; acc[r][1] = 0.f; }

        const float* eb = emb_t + q * kc + 2 * t;
        #pragma unroll 4
        for (int d = 0; d < DDIM; ++d) {
            const float2 e = *(const float2*)&eb[(size_t)d * K];
            #pragma unroll
            for (int r = 0; r < RPB; ++r) {
                const float xv = xs[r][d];
                acc[r][0] = fmaf(xv, e.x, acc[r][0]);
                acc[r][1] = fmaf(xv, e.y, acc[r][1]);
            }
        }

        const int k0 = q * kc + 2 * t;
        const float en0 = enorm2[k0], en1 = enorm2[k0 + 1];
        #pragma unroll
        for (int r = 0; r < RPB; ++r) {
            const float s0 = fmaf(-2.0f, acc[r][0], en0);
            const float s1 = fmaf(-2.0f, acc[r][1], en1);
            float bd = s0; int bk = k0;
            if (s1 < bd) { bd = s1; bk = k0 + 1; }
            #pragma unroll
            for (int m = 1; m < 64; m <<= 1) {
                const float od = __shfl_xor(bd, m, 64);
                const int   ok = __shfl_xor(bk, m, 64);
                if (od < bd || (od == bd && ok < bk)) { bd = od; bk = ok; }
            }
            if (l == 0) atomicMin(&packed[rows[r]], packdk(bd, bk));
        }
    }
}

// ---------------- gather: codes + quantized (rescue-aware) ------------------
__global__ void gather_q(const float* __restrict__ emb,
                         const int* __restrict__ codes_i,
                         const int* __restrict__ flags,
                         const u64* __restrict__ packed,
                         float* __restrict__ qout,
                         float* __restrict__ codes_f) {
    const int n = blockIdx.x * 4 + (threadIdx.x >> 6);
    const int c = threadIdx.x & 63;
    int k = codes_i[n];
    if (flags[n]) k = (int)(packed[n] & 0xFFFFFFFFull);
    if (c == 0) codes_f[n] = (float)k;
    *(float4*)&qout[(size_t)n * DDIM + c * 4] =
        *(const float4*)&emb[(size_t)k * DDIM + c * 4];
}

extern "C" void kernel_launch(void* const* d_in, const int* in_sizes, int n_in,
                              void* d_out, int out_size, void* d_ws, size_t ws_size,
                              hipStream_t stream) {
    const float* x     = (const float*)d_in[0];
    const float* esum  = (const float*)d_in[1];
    const float* usage = (const float*)d_in[2];
    const int K = in_sizes[2];                 // 2048
    const int N = in_sizes[0] / DDIM;          // 32768

    // workspace layout (packed first: 8B alignment)
    char* p = (char*)d_ws;
    u64*   packed  = (u64*)p;                  p += (size_t)N * 8;             // 256 KB
    float* emb     = (float*)p;                p += (size_t)K * DDIM * 4;      // 2 MB
    float* emb_t   = (float*)p;                p += (size_t)K * DDIM * 4;      // 2 MB
    float* enorm2  = (float*)p;                p += (size_t)K * 4;
    u32*   pp1     = (u32*)p;                  p += (size_t)NPART * N * 4;     // 512 KB
    u32*   pp2     = (u32*)p;                  p += (size_t)NPART * N * 4;     // 512 KB
    int*   codes_i = (int*)p;                  p += (size_t)N * 4;
    int*   flags   = (int*)p;                  p += (size_t)N * 4;
    int*   list    = (int*)p;                  p += (size_t)N * 4;
    int*   counter = (int*)p;                  p += 256;
    u16*   xh      = (u16*)p;                  p += (size_t)N * DDIM * 2;      // 16 MB
    u16*   eh      = (u16*)p;                  p += (size_t)K * DDIM * 2;      // 1 MB

    float* qout    = (float*)d_out;            // N*256
    float* codes_f = qout + (size_t)N * DDIM;  // N

    prep<<<K + N / 4, 256, 0, stream>>>(esum, usage, x, emb, emb_t, eh,
                                        enorm2, xh, counter, K);
    vq_mfma<<<(N / BM) * NPART, 256, 0, stream>>>(xh, eh, enorm2, pp1, pp2, N);
    combine<<<N / 256, 256, 0, stream>>>(pp1, pp2, codes_i, flags,
                                         list, counter, packed, N);
    rescue_c<<<1024, 256, 0, stream>>>(x, emb_t, enorm2, list, counter, packed, K);
    gather_q<<<N / 4, 256, 0, stream>>>(emb, codes_i, flags, packed, qout, codes_f);
}